// Round 1
// baseline (4424.714 us; speedup 1.0000x reference)
//
#include <hip/hip_runtime.h>
#include <hip/hip_bf16.h>
#include <cstddef>

// Problem constants
#define BB   8
#define CIN  16
#define COUT 16
#define TT   32
#define HH   16
#define WW   16
#define DIN  4096
#define DOUT 4096
#define NH   4
#define DH   1024
#define SPAT 8192            // T*H*W
#define NSEQ 256             // B*T

// ---------------------------------------------------------------------------
// conv3d 3x3x3 pad=1, in (B,16,32,16,16) -> out (B,16,32,16,16), + bias, opt relu
// grid: 4096 blocks x 256 threads; each block = one (b,o,t) slice (h,w vary)
// ---------------------------------------------------------------------------
__global__ void conv3d_kernel(const float* __restrict__ in,
                              const float* __restrict__ w,
                              const float* __restrict__ bias,
                              float* __restrict__ out, int relu) {
    __shared__ float ws[CIN * 27];
    int idx = blockIdx.x * 256 + threadIdx.x;
    int hw = idx & 255;
    int t  = (idx >> 8) & 31;
    int o  = (idx >> 13) & 15;
    int b  = idx >> 17;

    for (int i = threadIdx.x; i < CIN * 27; i += 256) ws[i] = w[o * CIN * 27 + i];
    __syncthreads();

    int h = hw >> 4, wx = hw & 15;
    float acc = bias[o];
    for (int ci = 0; ci < CIN; ++ci) {
        const float* xin = in + ((size_t)(b * CIN + ci) * TT) * 256;
        #pragma unroll
        for (int kt = 0; kt < 3; ++kt) {
            int tt = t + kt - 1;
            if ((unsigned)tt >= TT) continue;
            #pragma unroll
            for (int kh = 0; kh < 3; ++kh) {
                int h2 = h + kh - 1;
                if ((unsigned)h2 >= HH) continue;
                #pragma unroll
                for (int kw = 0; kw < 3; ++kw) {
                    int w2 = wx + kw - 1;
                    if ((unsigned)w2 >= WW) continue;
                    acc += xin[tt * 256 + h2 * 16 + w2] * ws[ci * 27 + kt * 9 + kh * 3 + kw];
                }
            }
        }
    }
    if (relu) acc = fmaxf(acc, 0.f);
    out[idx] = acc;
}

// ---------------------------------------------------------------------------
// instance norm over (T,H,W) per (b,c) + relu, in place. 128 blocks.
// ---------------------------------------------------------------------------
__global__ void inorm_relu_kernel(float* __restrict__ y) {
    __shared__ float s1[256], s2[256];
    float* p = y + (size_t)blockIdx.x * SPAT;
    float sum = 0.f, sq = 0.f;
    for (int i = threadIdx.x; i < SPAT; i += 256) {
        float v = p[i];
        sum += v; sq += v * v;
    }
    s1[threadIdx.x] = sum; s2[threadIdx.x] = sq;
    __syncthreads();
    for (int s = 128; s > 0; s >>= 1) {
        if (threadIdx.x < s) { s1[threadIdx.x] += s1[threadIdx.x + s]; s2[threadIdx.x] += s2[threadIdx.x + s]; }
        __syncthreads();
    }
    float mu = s1[0] / (float)SPAT;
    float var = s2[0] / (float)SPAT - mu * mu;
    float rs = rsqrtf(var + 1e-5f);
    for (int i = threadIdx.x; i < SPAT; i += 256) {
        float v = (p[i] - mu) * rs;
        p[i] = fmaxf(v, 0.f);
    }
}

// ---------------------------------------------------------------------------
// GEMM: C[n][o] = sum_k A[n][k] * Wt[o][k] + bias[o]
// A is the x-transpose view: A[n][k] with n=b*32+t, k=c*256+hw -> x[b][c][t][hw]
// tiles 32x32x32, 256 threads; grid (O/32, N/32)
// ---------------------------------------------------------------------------
#define GTS 32
__global__ void gemm_pre_kernel(const float* __restrict__ x,
                                const float* __restrict__ Wt,
                                const float* __restrict__ bias,
                                float* __restrict__ C, int K, int O) {
    __shared__ float As[GTS][GTS + 1];
    __shared__ float Bs[GTS][GTS + 1];
    int tx = threadIdx.x & 31;
    int ty = threadIdx.x >> 5;
    int o0 = blockIdx.x * GTS;
    int n0 = blockIdx.y * GTS;
    float acc[4] = {0.f, 0.f, 0.f, 0.f};
    for (int k0 = 0; k0 < K; k0 += GTS) {
        #pragma unroll
        for (int r = 0; r < 4; ++r) {
            int i = ty + 8 * r;
            int n = n0 + i, k = k0 + tx;
            int b = n >> 5, t = n & 31;
            int c = k >> 8, hw = k & 255;
            As[i][tx] = x[(((size_t)(b * CIN + c) * TT + t)) * 256 + hw];
        }
        #pragma unroll
        for (int r = 0; r < 4; ++r) {
            int i = ty + 8 * r;
            Bs[i][tx] = Wt[(size_t)(o0 + i) * K + k0 + tx];
        }
        __syncthreads();
        #pragma unroll
        for (int kk = 0; kk < GTS; ++kk) {
            float bv = Bs[tx][kk];
            #pragma unroll
            for (int r = 0; r < 4; ++r) acc[r] += As[ty + 8 * r][kk] * bv;
        }
        __syncthreads();
    }
    #pragma unroll
    for (int r = 0; r < 4; ++r) {
        int n = n0 + ty + 8 * r;
        C[(size_t)n * O + o0 + tx] = acc[r] + bias[o0 + tx];
    }
}

__global__ void gemm_kernel(const float* __restrict__ A,
                            const float* __restrict__ Wt,
                            const float* __restrict__ bias,
                            float* __restrict__ C, int K, int O) {
    __shared__ float As[GTS][GTS + 1];
    __shared__ float Bs[GTS][GTS + 1];
    int tx = threadIdx.x & 31;
    int ty = threadIdx.x >> 5;
    int o0 = blockIdx.x * GTS;
    int n0 = blockIdx.y * GTS;
    float acc[4] = {0.f, 0.f, 0.f, 0.f};
    for (int k0 = 0; k0 < K; k0 += GTS) {
        #pragma unroll
        for (int r = 0; r < 4; ++r) {
            int i = ty + 8 * r;
            As[i][tx] = A[(size_t)(n0 + i) * K + k0 + tx];
        }
        #pragma unroll
        for (int r = 0; r < 4; ++r) {
            int i = ty + 8 * r;
            Bs[i][tx] = Wt[(size_t)(o0 + i) * K + k0 + tx];
        }
        __syncthreads();
        #pragma unroll
        for (int kk = 0; kk < GTS; ++kk) {
            float bv = Bs[tx][kk];
            #pragma unroll
            for (int r = 0; r < 4; ++r) acc[r] += As[ty + 8 * r][kk] * bv;
        }
        __syncthreads();
    }
    #pragma unroll
    for (int r = 0; r < 4; ++r) {
        int n = n0 + ty + 8 * r;
        C[(size_t)n * O + o0 + tx] = acc[r] + bias[o0 + tx];
    }
}

// ---------------------------------------------------------------------------
// recurrent gh GEMM: gh[head][gate][b][o] = sum_d h[b][head*1024+d] * R[head][gate][o][d]
// grid: 256 blocks = head(4) x gate(4) x otile(16, 64 o each); 256 threads
// ---------------------------------------------------------------------------
__global__ void step_gh_kernel(const float* __restrict__ h_state,
                               const float* __restrict__ R,
                               float* __restrict__ gh) {
    __shared__ float Rs[64][33];
    __shared__ float Hs[8][33];
    int blk = blockIdx.x;
    int otile = blk & 15;
    int gate  = (blk >> 4) & 3;
    int head  = blk >> 6;
    int o0 = otile * 64;
    const float* Rbase = R + ((size_t)(head * 4 + gate) * DH + o0) * DH;
    int tid = threadIdx.x;
    int o_l = tid & 63;
    int bp  = tid >> 6;   // batch pair 0..3
    float acc0 = 0.f, acc1 = 0.f;
    for (int k0 = 0; k0 < DH; k0 += 32) {
        for (int i = tid; i < 64 * 32; i += 256) {
            int r = i >> 5, kk = i & 31;
            Rs[r][kk] = Rbase[(size_t)r * DH + k0 + kk];
        }
        if (tid < 8 * 32) {
            int bb = tid >> 5, kk = tid & 31;
            Hs[bb][kk] = h_state[bb * DOUT + head * DH + k0 + kk];
        }
        __syncthreads();
        #pragma unroll
        for (int kk = 0; kk < 32; ++kk) {
            float rv = Rs[o_l][kk];
            acc0 += Hs[2 * bp][kk] * rv;
            acc1 += Hs[2 * bp + 1][kk] * rv;
        }
        __syncthreads();
    }
    float* outp = gh + (size_t)(head * 4 + gate) * 8 * DH;
    outp[(2 * bp) * DH + o0 + o_l]     = acc0;
    outp[(2 * bp + 1) * DH + o0 + o_l] = acc1;
}

// ---------------------------------------------------------------------------
// gate elementwise for step t. 128 blocks x 256 threads = 32768 = B*DOUT
// ---------------------------------------------------------------------------
__global__ void step_gate_kernel(const float* __restrict__ Gx,
                                 const float* __restrict__ gh,
                                 float* __restrict__ h, float* __restrict__ c,
                                 float* __restrict__ n, float* __restrict__ m,
                                 float* __restrict__ hs, int t) {
    int idx = blockIdx.x * 256 + threadIdx.x;   // b*4096 + d
    int b = idx >> 12;
    int d = idx & 4095;
    int head = d >> 10, o = d & 1023;
    const float* gx = Gx + ((size_t)(b * TT + t)) * 4 * DOUT;
    float ip = gx[0 * DOUT + d] + gh[(size_t)((head * 4 + 0) * 8 + b) * DH + o];
    float fp = gx[1 * DOUT + d] + gh[(size_t)((head * 4 + 1) * 8 + b) * DH + o];
    float zp = gx[2 * DOUT + d] + gh[(size_t)((head * 4 + 2) * 8 + b) * DH + o];
    float op = gx[3 * DOUT + d] + gh[(size_t)((head * 4 + 3) * 8 + b) * DH + o];
    float mo = m[idx];
    float mn = fmaxf(fp + mo, ip);
    float iv = expf(ip - mn);
    float fv = expf(fp + mo - mn);
    float cv = fv * c[idx] + iv * tanhf(zp);
    float nv = fv * n[idx] + iv;
    float sig = 1.f / (1.f + expf(-op));
    float hv = sig * cv / nv;
    c[idx] = cv; n[idx] = nv; m[idx] = mn; h[idx] = hv;
    hs[((size_t)(b * TT + t)) * DOUT + d] = hv;
}

// ---------------------------------------------------------------------------
// final combine: alpha = sigmoid(attn_w . [s_out; out3d] + attn_b)
// out = alpha*out3d + (1-alpha)*s_out.  65536 positions (b,t,hw).
// ---------------------------------------------------------------------------
__global__ void combine_kernel(const float* __restrict__ hs,
                               const float* __restrict__ out3d,
                               const float* __restrict__ attn_w,
                               const float* __restrict__ attn_b,
                               float* __restrict__ out) {
    int idx = blockIdx.x * 256 + threadIdx.x;
    int hw = idx & 255;
    int t  = (idx >> 8) & 31;
    int b  = idx >> 13;
    const float* hrow = hs + ((size_t)(b * TT + t)) * DOUT;
    float dot = attn_b[0];
    float sv[16], ov[16];
    #pragma unroll
    for (int ch = 0; ch < 16; ++ch) {
        float s  = hrow[ch * 256 + hw];
        float o3 = out3d[(((size_t)(b * COUT + ch) * TT + t)) * 256 + hw];
        sv[ch] = s; ov[ch] = o3;
        dot += attn_w[ch] * s + attn_w[16 + ch] * o3;
    }
    float alpha = 1.f / (1.f + expf(-dot));
    #pragma unroll
    for (int ch = 0; ch < 16; ++ch) {
        out[(((size_t)(b * COUT + ch) * TT + t)) * 256 + hw] =
            alpha * ov[ch] + (1.f - alpha) * sv[ch];
    }
}

// ---------------------------------------------------------------------------
extern "C" void kernel_launch(void* const* d_in, const int* in_sizes, int n_in,
                              void* d_out, int out_size, void* d_ws, size_t ws_size,
                              hipStream_t stream) {
    const float* x      = (const float*)d_in[0];
    const float* c1_w   = (const float*)d_in[1];
    const float* c1_b   = (const float*)d_in[2];
    const float* c2_w   = (const float*)d_in[3];
    const float* c2_b   = (const float*)d_in[4];
    const float* c3_w   = (const float*)d_in[5];
    const float* c3_b   = (const float*)d_in[6];
    const float* pre_w  = (const float*)d_in[7];
    const float* pre_b  = (const float*)d_in[8];
    const float* lstm_W = (const float*)d_in[9];
    const float* lstm_b = (const float*)d_in[10];
    const float* lstm_R = (const float*)d_in[11];
    const float* attn_w = (const float*)d_in[12];
    const float* attn_b = (const float*)d_in[13];
    float* out = (float*)d_out;

    float* ws   = (float*)d_ws;
    float* y1    = ws;                 // 1048576
    float* y2    = y1 + 1048576;       // 1048576
    float* out3d = y2 + 1048576;       // 1048576
    float* xs2   = out3d + 1048576;    // 1048576  (pre-projection output)
    float* hs    = xs2 + 1048576;      // 1048576
    float* Gx    = hs + 1048576;       // 4194304
    float* gh    = Gx + 4194304;       // 131072
    float* st_h  = gh + 131072;        // 32768
    float* st_c  = st_h + 32768;       // 32768
    float* st_n  = st_c + 32768;       // 32768
    float* st_m  = st_n + 32768;       // 32768

    // zero recurrent state (h,c,n,m contiguous)
    hipMemsetAsync(st_h, 0, 4 * 32768 * sizeof(float), stream);

    // conv1 (raw+bias) -> y1; instance-norm+relu in place
    conv3d_kernel<<<4096, 256, 0, stream>>>(x, c1_w, c1_b, y1, 0);
    inorm_relu_kernel<<<128, 256, 0, stream>>>(y1);
    // conv2 + relu -> y2 ; conv3 + relu -> out3d
    conv3d_kernel<<<4096, 256, 0, stream>>>(y1, c2_w, c2_b, y2, 1);
    conv3d_kernel<<<4096, 256, 0, stream>>>(y2, c3_w, c3_b, out3d, 1);

    // pre-projection: xs2[n][o], n=b*32+t   (A read from x with transpose)
    gemm_pre_kernel<<<dim3(DOUT / GTS, NSEQ / GTS), 256, 0, stream>>>(
        x, pre_w, pre_b, xs2, DIN, DOUT);

    // gate projection: Gx[n][g*4096+o] = xs2 @ lstm_W^T + lstm_b
    gemm_kernel<<<dim3(4 * DOUT / GTS, NSEQ / GTS), 256, 0, stream>>>(
        xs2, lstm_W, lstm_b, Gx, DOUT, 4 * DOUT);

    // recurrence
    for (int t = 0; t < TT; ++t) {
        step_gh_kernel<<<256, 256, 0, stream>>>(st_h, lstm_R, gh);
        step_gate_kernel<<<128, 256, 0, stream>>>(Gx, gh, st_h, st_c, st_n, st_m, hs, t);
    }

    // combine
    combine_kernel<<<256, 256, 0, stream>>>(hs, out3d, attn_w, attn_b, out);
}

// Round 2
// 1686.084 us; speedup vs baseline: 2.6243x; 2.6243x over previous
//
#include <hip/hip_runtime.h>
#include <hip/hip_bf16.h>
#include <cstddef>

// Problem constants
#define BB   8
#define CIN  16
#define COUT 16
#define TT   32
#define HH   16
#define WW   16
#define DIN  4096
#define DOUT 4096
#define NH   4
#define DH   1024
#define SPAT 8192            // T*H*W
#define NSEQ 256             // B*T

typedef __attribute__((ext_vector_type(8))) short  bf16x8;
typedef __attribute__((ext_vector_type(4))) float  f32x4;
typedef __attribute__((ext_vector_type(4))) unsigned short us4;
typedef unsigned short ushort_t;

static __device__ __forceinline__ ushort_t f2bf(float f) {
    union { float f; unsigned u; } v; v.f = f;
    unsigned r = (v.u + 0x7fffu + ((v.u >> 16) & 1u)) >> 16;
    return (ushort_t)r;
}
static __device__ __forceinline__ float bf2f(ushort_t u) {
    union { unsigned u; float f; } v; v.u = ((unsigned)u) << 16;
    return v.f;
}

// ---------------------------------------------------------------------------
// pack x (B,16,32,16,16) fp32 -> xt[n=b*32+t][k=c*256+hw] bf16
// ---------------------------------------------------------------------------
__global__ void pack_xt_kernel(const float* __restrict__ x, ushort_t* __restrict__ xt) {
    int idx = blockIdx.x * 256 + threadIdx.x;          // 0 .. 262143 (4 elems each)
    int n = idx >> 10, k4 = (idx & 1023) * 4;
    int b = n >> 5, t = n & 31, c = k4 >> 8, hw = k4 & 255;
    f32x4 f = *(const f32x4*)&x[(((size_t)(b * CIN + c) * TT + t)) * 256 + hw];
    us4 o;
    #pragma unroll
    for (int i = 0; i < 4; ++i) o[i] = f2bf(f[i]);
    *(us4*)&xt[(size_t)n * DIN + k4] = o;
}

// generic fp32 -> bf16 (n multiple of 4)
__global__ void cvt_bf16_kernel(const float* __restrict__ in, ushort_t* __restrict__ out, int n4) {
    int i = blockIdx.x * 256 + threadIdx.x;
    int stride = gridDim.x * 256;
    for (; i < n4; i += stride) {
        f32x4 f = ((const f32x4*)in)[i];
        us4 o;
        #pragma unroll
        for (int j = 0; j < 4; ++j) o[j] = f2bf(f[j]);
        ((us4*)out)[i] = o;
    }
}

// ---------------------------------------------------------------------------
// MFMA GEMM: C[M][N] = A[M][K](bf16) * B[N][K]^T + bias[N]
// BM=128 BN=64 BK=64, 256 threads (4 waves), double-buffered LDS.
// B_BF16: B is bf16 (staged via global_load_lds) else fp32 (reg-stage+convert).
// OUT_BF16: write bf16 else fp32.
// ---------------------------------------------------------------------------
#define GBM 128
#define GBN 64
#define GBK 64

template<bool B_BF16, bool OUT_BF16>
__global__ __launch_bounds__(256, 2)
void mfma_gemm_kernel(const ushort_t* __restrict__ A, const void* __restrict__ Bv,
                      const float* __restrict__ bias, void* __restrict__ C,
                      int M, int N, int K) {
    __shared__ ushort_t Al[2][GBM][GBK];   // 32 KB
    __shared__ ushort_t Bl[2][GBN][GBK];   // 16 KB
    int tid  = threadIdx.x;
    int lane = tid & 63;
    int wv   = tid >> 6;       // 0..3
    int wr   = wv >> 1;        // wave-row (64 M-rows each)
    int wc   = wv & 1;         // wave-col (32 N-cols each)
    int m0 = blockIdx.y * GBM;
    int n0 = blockIdx.x * GBN;

    f32x4 acc[4][2];
    #pragma unroll
    for (int i = 0; i < 4; ++i)
        #pragma unroll
        for (int j = 0; j < 2; ++j) acc[i][j] = (f32x4){0.f, 0.f, 0.f, 0.f};

    auto stageA = [&](int buf, int k0) {
        #pragma unroll
        for (int q = 0; q < 4; ++q) {
            int row = wv * 32 + q * 8 + (lane >> 3);
            const ushort_t* g = A + (size_t)(m0 + row) * K + k0 + (lane & 7) * 8;
            __builtin_amdgcn_global_load_lds(
                (const __attribute__((address_space(1))) void*)g,
                (__attribute__((address_space(3))) void*)&Al[buf][wv * 32 + q * 8][0],
                16, 0, 0);
        }
    };
    auto stageB = [&](int buf, int k0) {
        if constexpr (B_BF16) {
            const ushort_t* B = (const ushort_t*)Bv;
            #pragma unroll
            for (int q = 0; q < 2; ++q) {
                int row = wv * 16 + q * 8 + (lane >> 3);
                const ushort_t* g = B + (size_t)(n0 + row) * K + k0 + (lane & 7) * 8;
                __builtin_amdgcn_global_load_lds(
                    (const __attribute__((address_space(1))) void*)g,
                    (__attribute__((address_space(3))) void*)&Bl[buf][wv * 16 + q * 8][0],
                    16, 0, 0);
            }
        } else {
            const float* B = (const float*)Bv;
            int r = tid >> 2;               // 0..63
            int cs = (tid & 3) * 16;        // 0,16,32,48
            const float* g = B + (size_t)(n0 + r) * K + k0 + cs;
            f32x4 f0 = *(const f32x4*)(g);
            f32x4 f1 = *(const f32x4*)(g + 4);
            f32x4 f2 = *(const f32x4*)(g + 8);
            f32x4 f3 = *(const f32x4*)(g + 12);
            union { ushort_t u[16]; bf16x8 v[2]; } pk;
            #pragma unroll
            for (int i = 0; i < 4; ++i) {
                pk.u[i]      = f2bf(f0[i]);
                pk.u[4 + i]  = f2bf(f1[i]);
                pk.u[8 + i]  = f2bf(f2[i]);
                pk.u[12 + i] = f2bf(f3[i]);
            }
            *(bf16x8*)&Bl[buf][r][cs]     = pk.v[0];
            *(bf16x8*)&Bl[buf][r][cs + 8] = pk.v[1];
        }
    };
    auto compute = [&](int buf) {
        #pragma unroll
        for (int ks = 0; ks < 2; ++ks) {
            bf16x8 af[4], bfr[2];
            #pragma unroll
            for (int i = 0; i < 4; ++i)
                af[i] = *(const bf16x8*)&Al[buf][wr * 64 + i * 16 + (lane & 15)][ks * 32 + (lane >> 4) * 8];
            #pragma unroll
            for (int j = 0; j < 2; ++j)
                bfr[j] = *(const bf16x8*)&Bl[buf][wc * 32 + j * 16 + (lane & 15)][ks * 32 + (lane >> 4) * 8];
            #pragma unroll
            for (int i = 0; i < 4; ++i)
                #pragma unroll
                for (int j = 0; j < 2; ++j)
                    acc[i][j] = __builtin_amdgcn_mfma_f32_16x16x32_bf16(af[i], bfr[j], acc[i][j], 0, 0, 0);
        }
    };

    stageA(0, 0); stageB(0, 0);
    __syncthreads();
    int nk = K / GBK;
    int cur = 0;
    for (int t = 0; t < nk; ++t) {
        if (t + 1 < nk) { stageA(cur ^ 1, (t + 1) * GBK); stageB(cur ^ 1, (t + 1) * GBK); }
        compute(cur);
        __syncthreads();
        cur ^= 1;
    }

    #pragma unroll
    for (int i = 0; i < 4; ++i) {
        int row = m0 + wr * 64 + i * 16 + (lane >> 4) * 4;
        #pragma unroll
        for (int j = 0; j < 2; ++j) {
            int col = n0 + wc * 32 + j * 16 + (lane & 15);
            float bv = bias[col];
            #pragma unroll
            for (int r = 0; r < 4; ++r) {
                float v = acc[i][j][r] + bv;
                if constexpr (OUT_BF16) ((ushort_t*)C)[(size_t)(row + r) * N + col] = f2bf(v);
                else                    ((float*)C)[(size_t)(row + r) * N + col] = v;
            }
        }
    }
}

// ---------------------------------------------------------------------------
// conv3d 3x3x3 pad=1: one block per (b,t); LDS-staged input slice + weights.
// Each thread: one hw, all 16 output channels.
// ---------------------------------------------------------------------------
__global__ __launch_bounds__(256)
void conv3d_kernel(const float* __restrict__ in, const float* __restrict__ w,
                   const float* __restrict__ bias, float* __restrict__ out, int relu) {
    __shared__ float xin[CIN][3][256];      // 48 KB
    __shared__ float wl[CIN][27][16];       // 27 KB, o-fastest
    int b = blockIdx.x >> 5, t = blockIdx.x & 31;
    int tid = threadIdx.x;

    for (int i = tid; i < CIN * 27 * 16; i += 256) {
        int o = i & 15, r = i >> 4;
        int k = r % 27, ci = r / 27;
        wl[ci][k][o] = w[(size_t)(o * CIN + ci) * 27 + k];
    }
    for (int i = tid; i < CIN * 3 * 256; i += 256) {
        int hw = i & 255, r = i >> 8;
        int kt = r % 3, ci = r / 3;
        int tt = t + kt - 1;
        xin[ci][kt][hw] = ((unsigned)tt < TT)
            ? in[((size_t)(b * CIN + ci) * TT + tt) * 256 + hw] : 0.f;
    }
    __syncthreads();

    int h = tid >> 4, wx = tid & 15;
    f32x4 a0 = *(const f32x4*)&bias[0];
    f32x4 a1 = *(const f32x4*)&bias[4];
    f32x4 a2 = *(const f32x4*)&bias[8];
    f32x4 a3 = *(const f32x4*)&bias[12];

    for (int ci = 0; ci < CIN; ++ci) {
        #pragma unroll
        for (int kt = 0; kt < 3; ++kt) {
            #pragma unroll
            for (int kh = 0; kh < 3; ++kh) {
                int h2 = h + kh - 1;
                if ((unsigned)h2 >= HH) continue;
                #pragma unroll
                for (int kw = 0; kw < 3; ++kw) {
                    int w2 = wx + kw - 1;
                    if ((unsigned)w2 >= WW) continue;
                    float xv = xin[ci][kt][h2 * 16 + w2];
                    int k = kt * 9 + kh * 3 + kw;
                    f32x4 w0 = *(const f32x4*)&wl[ci][k][0];
                    f32x4 w1 = *(const f32x4*)&wl[ci][k][4];
                    f32x4 w2v = *(const f32x4*)&wl[ci][k][8];
                    f32x4 w3 = *(const f32x4*)&wl[ci][k][12];
                    a0 += xv * w0; a1 += xv * w1; a2 += xv * w2v; a3 += xv * w3;
                }
            }
        }
    }
    float accs[16];
    #pragma unroll
    for (int i = 0; i < 4; ++i) { accs[i] = a0[i]; accs[4+i] = a1[i]; accs[8+i] = a2[i]; accs[12+i] = a3[i]; }
    #pragma unroll
    for (int o = 0; o < 16; ++o) {
        float v = accs[o];
        if (relu) v = fmaxf(v, 0.f);
        out[((size_t)(b * COUT + o) * TT + t) * 256 + tid] = v;
    }
}

// ---------------------------------------------------------------------------
// instance norm over (T,H,W) per (b,c) + relu, in place. 128 blocks.
// ---------------------------------------------------------------------------
__global__ void inorm_relu_kernel(float* __restrict__ y) {
    __shared__ float s1[256], s2[256];
    float* p = y + (size_t)blockIdx.x * SPAT;
    float sum = 0.f, sq = 0.f;
    for (int i = threadIdx.x; i < SPAT; i += 256) {
        float v = p[i];
        sum += v; sq += v * v;
    }
    s1[threadIdx.x] = sum; s2[threadIdx.x] = sq;
    __syncthreads();
    for (int s = 128; s > 0; s >>= 1) {
        if (threadIdx.x < s) { s1[threadIdx.x] += s1[threadIdx.x + s]; s2[threadIdx.x] += s2[threadIdx.x + s]; }
        __syncthreads();
    }
    float mu = s1[0] / (float)SPAT;
    float var = s2[0] / (float)SPAT - mu * mu;
    float rs = rsqrtf(var + 1e-5f);
    for (int i = threadIdx.x; i < SPAT; i += 256) {
        float v = (p[i] - mu) * rs;
        p[i] = fmaxf(v, 0.f);
    }
}

// ---------------------------------------------------------------------------
// recurrent gh GEMM: gh[head][gate][b][o] = sum_d h[b][head*1024+d] * R[hgod]
// 256 blocks = head(4) x gate(4) x otile(16 of 64); 256 threads
// ---------------------------------------------------------------------------
template<bool RBF>
__global__ void step_gh_kernel(const float* __restrict__ h_state,
                               const void* __restrict__ Rv,
                               float* __restrict__ gh) {
    __shared__ float Rs[64][33];
    __shared__ float Hs[8][33];
    int blk = blockIdx.x;
    int otile = blk & 15;
    int gate  = (blk >> 4) & 3;
    int head  = blk >> 6;
    int o0 = otile * 64;
    size_t rbase = ((size_t)(head * 4 + gate) * DH + o0) * DH;
    int tid = threadIdx.x;
    int o_l = tid & 63;
    int bp  = tid >> 6;   // batch pair 0..3
    float acc0 = 0.f, acc1 = 0.f;
    for (int k0 = 0; k0 < DH; k0 += 32) {
        if constexpr (RBF) {
            const ushort_t* Rb = (const ushort_t*)Rv;
            int r = tid >> 2, seg = (tid & 3) * 8;
            bf16x8 v = *(const bf16x8*)&Rb[rbase + (size_t)r * DH + k0 + seg];
            #pragma unroll
            for (int j = 0; j < 8; ++j) Rs[r][seg + j] = bf2f((ushort_t)v[j]);
        } else {
            const float* Rf = (const float*)Rv;
            for (int i = tid; i < 64 * 32; i += 256) {
                int r = i >> 5, kk = i & 31;
                Rs[r][kk] = Rf[rbase + (size_t)r * DH + k0 + kk];
            }
        }
        if (tid < 8 * 32) {
            int bb = tid >> 5, kk = tid & 31;
            Hs[bb][kk] = h_state[bb * DOUT + head * DH + k0 + kk];
        }
        __syncthreads();
        #pragma unroll
        for (int kk = 0; kk < 32; ++kk) {
            float rv = Rs[o_l][kk];
            acc0 += Hs[2 * bp][kk] * rv;
            acc1 += Hs[2 * bp + 1][kk] * rv;
        }
        __syncthreads();
    }
    float* outp = gh + (size_t)(head * 4 + gate) * 8 * DH;
    outp[(2 * bp) * DH + o0 + o_l]     = acc0;
    outp[(2 * bp + 1) * DH + o0 + o_l] = acc1;
}

// ---------------------------------------------------------------------------
// gate elementwise for step t. 128 blocks x 256 threads = 32768 = B*DOUT
// ---------------------------------------------------------------------------
__global__ void step_gate_kernel(const float* __restrict__ Gx,
                                 const float* __restrict__ gh,
                                 float* __restrict__ h, float* __restrict__ c,
                                 float* __restrict__ n, float* __restrict__ m,
                                 float* __restrict__ hs, int t) {
    int idx = blockIdx.x * 256 + threadIdx.x;   // b*4096 + d
    int b = idx >> 12;
    int d = idx & 4095;
    int head = d >> 10, o = d & 1023;
    const float* gx = Gx + ((size_t)(b * TT + t)) * 4 * DOUT;
    float ip = gx[0 * DOUT + d] + gh[(size_t)((head * 4 + 0) * 8 + b) * DH + o];
    float fp = gx[1 * DOUT + d] + gh[(size_t)((head * 4 + 1) * 8 + b) * DH + o];
    float zp = gx[2 * DOUT + d] + gh[(size_t)((head * 4 + 2) * 8 + b) * DH + o];
    float op = gx[3 * DOUT + d] + gh[(size_t)((head * 4 + 3) * 8 + b) * DH + o];
    float mo = m[idx];
    float mn = fmaxf(fp + mo, ip);
    float iv = expf(ip - mn);
    float fv = expf(fp + mo - mn);
    float cv = fv * c[idx] + iv * tanhf(zp);
    float nv = fv * n[idx] + iv;
    float sig = 1.f / (1.f + expf(-op));
    float hv = sig * cv / nv;
    c[idx] = cv; n[idx] = nv; m[idx] = mn; h[idx] = hv;
    hs[((size_t)(b * TT + t)) * DOUT + d] = hv;
}

// ---------------------------------------------------------------------------
// final combine
// ---------------------------------------------------------------------------
__global__ void combine_kernel(const float* __restrict__ hs,
                               const float* __restrict__ out3d,
                               const float* __restrict__ attn_w,
                               const float* __restrict__ attn_b,
                               float* __restrict__ out) {
    int idx = blockIdx.x * 256 + threadIdx.x;
    int hw = idx & 255;
    int t  = (idx >> 8) & 31;
    int b  = idx >> 13;
    const float* hrow = hs + ((size_t)(b * TT + t)) * DOUT;
    float dot = attn_b[0];
    float sv[16], ov[16];
    #pragma unroll
    for (int ch = 0; ch < 16; ++ch) {
        float s  = hrow[ch * 256 + hw];
        float o3 = out3d[(((size_t)(b * COUT + ch) * TT + t)) * 256 + hw];
        sv[ch] = s; ov[ch] = o3;
        dot += attn_w[ch] * s + attn_w[16 + ch] * o3;
    }
    float alpha = 1.f / (1.f + expf(-dot));
    #pragma unroll
    for (int ch = 0; ch < 16; ++ch) {
        out[(((size_t)(b * COUT + ch) * TT + t)) * 256 + hw] =
            alpha * ov[ch] + (1.f - alpha) * sv[ch];
    }
}

// ---------------------------------------------------------------------------
extern "C" void kernel_launch(void* const* d_in, const int* in_sizes, int n_in,
                              void* d_out, int out_size, void* d_ws, size_t ws_size,
                              hipStream_t stream) {
    const float* x      = (const float*)d_in[0];
    const float* c1_w   = (const float*)d_in[1];
    const float* c1_b   = (const float*)d_in[2];
    const float* c2_w   = (const float*)d_in[3];
    const float* c2_b   = (const float*)d_in[4];
    const float* c3_w   = (const float*)d_in[5];
    const float* c3_b   = (const float*)d_in[6];
    const float* pre_w  = (const float*)d_in[7];
    const float* pre_b  = (const float*)d_in[8];
    const float* lstm_W = (const float*)d_in[9];
    const float* lstm_b = (const float*)d_in[10];
    const float* lstm_R = (const float*)d_in[11];
    const float* attn_w = (const float*)d_in[12];
    const float* attn_b = (const float*)d_in[13];
    float* out = (float*)d_out;

    // fp32 workspace carve
    float* wsf = (float*)d_ws;
    float* y1    = wsf;                // 1048576
    float* y2    = y1 + 1048576;       // 1048576
    float* out3d = y2 + 1048576;       // 1048576
    float* hs    = out3d + 1048576;    // 1048576
    float* Gx    = hs + 1048576;       // 4194304
    float* gh    = Gx + 4194304;       // 131072
    float* st_h  = gh + 131072;        // 32768
    float* st_c  = st_h + 32768;
    float* st_n  = st_c + 32768;
    float* st_m  = st_n + 32768;
    // bf16 region
    ushort_t* xt    = (ushort_t*)(st_m + 32768);
    ushort_t* xs2b  = xt + 1048576;
    ushort_t* R_bf  = xs2b + 1048576;       // 16777216 (tier >= B)
    ushort_t* pw_bf = R_bf + 16777216;      // 16777216 (tier A)
    ushort_t* lw_bf = pw_bf + 16777216;     // 67108864 (tier A)

    size_t baseB  = (size_t)(8650752) * 4 + (size_t)2097152 * 2;
    size_t tierBB = baseB + (size_t)16777216 * 2;
    size_t tierAB = tierBB + (size_t)(16777216 + 67108864) * 2;
    bool tierB = ws_size >= tierBB;
    bool tierA = ws_size >= tierAB;

    // zero recurrent state (h,c,n,m contiguous)
    hipMemsetAsync(st_h, 0, 4 * 32768 * sizeof(float), stream);

    // pack/convert
    pack_xt_kernel<<<1024, 256, 0, stream>>>(x, xt);
    if (tierB) cvt_bf16_kernel<<<2048, 256, 0, stream>>>(lstm_R, R_bf, 16777216 / 4);
    if (tierA) {
        cvt_bf16_kernel<<<2048, 256, 0, stream>>>(pre_w, pw_bf, 16777216 / 4);
        cvt_bf16_kernel<<<4096, 256, 0, stream>>>(lstm_W, lw_bf, 67108864 / 4);
    }

    // convs
    conv3d_kernel<<<256, 256, 0, stream>>>(x, c1_w, c1_b, y1, 0);
    inorm_relu_kernel<<<128, 256, 0, stream>>>(y1);
    conv3d_kernel<<<256, 256, 0, stream>>>(y1, c2_w, c2_b, y2, 1);
    conv3d_kernel<<<256, 256, 0, stream>>>(y2, c3_w, c3_b, out3d, 1);

    // pre-projection -> xs2 (bf16), then gate projection -> Gx (fp32)
    if (tierA) {
        mfma_gemm_kernel<true, true><<<dim3(DOUT / GBN, NSEQ / GBM), 256, 0, stream>>>(
            xt, pw_bf, pre_b, xs2b, NSEQ, DOUT, DIN);
        mfma_gemm_kernel<true, false><<<dim3(4 * DOUT / GBN, NSEQ / GBM), 256, 0, stream>>>(
            xs2b, lw_bf, lstm_b, Gx, NSEQ, 4 * DOUT, DOUT);
    } else {
        mfma_gemm_kernel<false, true><<<dim3(DOUT / GBN, NSEQ / GBM), 256, 0, stream>>>(
            xt, pre_w, pre_b, xs2b, NSEQ, DOUT, DIN);
        mfma_gemm_kernel<false, false><<<dim3(4 * DOUT / GBN, NSEQ / GBM), 256, 0, stream>>>(
            xs2b, lstm_W, lstm_b, Gx, NSEQ, 4 * DOUT, DOUT);
    }

    // recurrence
    for (int t = 0; t < TT; ++t) {
        if (tierB) step_gh_kernel<true><<<256, 256, 0, stream>>>(st_h, R_bf, gh);
        else       step_gh_kernel<false><<<256, 256, 0, stream>>>(st_h, lstm_R, gh);
        step_gate_kernel<<<128, 256, 0, stream>>>(Gx, gh, st_h, st_c, st_n, st_m, hs, t);
    }

    // combine
    combine_kernel<<<256, 256, 0, stream>>>(hs, out3d, attn_w, attn_b, out);
}

// Round 3
// 894.428 us; speedup vs baseline: 4.9470x; 1.8851x over previous
//
#include <hip/hip_runtime.h>
#include <hip/hip_bf16.h>
#include <cstddef>

// Problem constants
#define BB   8
#define CIN  16
#define COUT 16
#define TT   32
#define HH   16
#define WW   16
#define DIN  4096
#define DOUT 4096
#define NH   4
#define DH   1024
#define SPAT 8192            // T*H*W
#define NSEQ 256             // B*T

typedef __attribute__((ext_vector_type(8))) short  bf16x8;
typedef __attribute__((ext_vector_type(4))) float  f32x4;
typedef __attribute__((ext_vector_type(4))) unsigned short us4;
typedef unsigned short ushort_t;

static __device__ __forceinline__ ushort_t f2bf(float f) {
    union { float f; unsigned u; } v; v.f = f;
    unsigned r = (v.u + 0x7fffu + ((v.u >> 16) & 1u)) >> 16;
    return (ushort_t)r;
}
static __device__ __forceinline__ float bf2f(ushort_t u) {
    union { unsigned u; float f; } v; v.u = ((unsigned)u) << 16;
    return v.f;
}

// ---------------------------------------------------------------------------
// pack x (B,16,32,16,16) fp32 -> xt[n=b*32+t][k=c*256+hw] bf16
// ---------------------------------------------------------------------------
__global__ void pack_xt_kernel(const float* __restrict__ x, ushort_t* __restrict__ xt) {
    int idx = blockIdx.x * 256 + threadIdx.x;          // 0 .. 262143 (4 elems each)
    int n = idx >> 10, k4 = (idx & 1023) * 4;
    int b = n >> 5, t = n & 31, c = k4 >> 8, hw = k4 & 255;
    f32x4 f = *(const f32x4*)&x[(((size_t)(b * CIN + c) * TT + t)) * 256 + hw];
    us4 o;
    #pragma unroll
    for (int i = 0; i < 4; ++i) o[i] = f2bf(f[i]);
    *(us4*)&xt[(size_t)n * DIN + k4] = o;
}

// generic fp32 -> bf16 (n multiple of 4)
__global__ void cvt_bf16_kernel(const float* __restrict__ in, ushort_t* __restrict__ out, int n4) {
    int i = blockIdx.x * 256 + threadIdx.x;
    int stride = gridDim.x * 256;
    for (; i < n4; i += stride) {
        f32x4 f = ((const f32x4*)in)[i];
        us4 o;
        #pragma unroll
        for (int j = 0; j < 4; ++j) o[j] = f2bf(f[j]);
        ((us4*)out)[i] = o;
    }
}

// ---------------------------------------------------------------------------
// MFMA GEMM, single M-tile: C[256][N] = A[256][K](bf16) * B[N][K]^T(fp32) + bias
// BM=256 BN=64 BK=64, 256 threads (4 waves), double-buffered LDS.
// B is fp32, converted to bf16 on the fly (read exactly once from HBM).
// ---------------------------------------------------------------------------
template<bool OUT_BF16>
__global__ __launch_bounds__(256, 2)
void mfma_gemm_kernel(const ushort_t* __restrict__ A, const float* __restrict__ B,
                      const float* __restrict__ bias, void* __restrict__ C,
                      int N, int K) {
    __shared__ ushort_t Al[2][256][64];   // 64 KB
    __shared__ ushort_t Bl[2][64][64];    // 16 KB
    int tid  = threadIdx.x;
    int lane = tid & 63;
    int wv   = tid >> 6;       // 0..3 : wave owns rows [wv*64, wv*64+64)
    int n0 = blockIdx.x * 64;

    f32x4 acc[4][4];
    #pragma unroll
    for (int i = 0; i < 4; ++i)
        #pragma unroll
        for (int j = 0; j < 4; ++j) acc[i][j] = (f32x4){0.f, 0.f, 0.f, 0.f};

    auto stageA = [&](int buf, int k0) {
        #pragma unroll
        for (int q = 0; q < 8; ++q) {
            int row = wv * 64 + q * 8 + (lane >> 3);
            const ushort_t* g = A + (size_t)row * K + k0 + (lane & 7) * 8;
            __builtin_amdgcn_global_load_lds(
                (const __attribute__((address_space(1))) void*)g,
                (__attribute__((address_space(3))) void*)&Al[buf][wv * 64 + q * 8][0],
                16, 0, 0);
        }
    };
    auto stageB = [&](int buf, int k0) {
        int r = tid >> 2;               // 0..63
        int cs = (tid & 3) * 16;        // 0,16,32,48
        const float* g = B + (size_t)(n0 + r) * K + k0 + cs;
        f32x4 f0 = *(const f32x4*)(g);
        f32x4 f1 = *(const f32x4*)(g + 4);
        f32x4 f2 = *(const f32x4*)(g + 8);
        f32x4 f3 = *(const f32x4*)(g + 12);
        union { ushort_t u[16]; bf16x8 v[2]; } pk;
        #pragma unroll
        for (int i = 0; i < 4; ++i) {
            pk.u[i]      = f2bf(f0[i]);
            pk.u[4 + i]  = f2bf(f1[i]);
            pk.u[8 + i]  = f2bf(f2[i]);
            pk.u[12 + i] = f2bf(f3[i]);
        }
        *(bf16x8*)&Bl[buf][r][cs]     = pk.v[0];
        *(bf16x8*)&Bl[buf][r][cs + 8] = pk.v[1];
    };
    auto compute = [&](int buf) {
        #pragma unroll
        for (int ks = 0; ks < 2; ++ks) {
            bf16x8 af[4], bfr[4];
            #pragma unroll
            for (int i = 0; i < 4; ++i)
                af[i] = *(const bf16x8*)&Al[buf][wv * 64 + i * 16 + (lane & 15)][ks * 32 + (lane >> 4) * 8];
            #pragma unroll
            for (int j = 0; j < 4; ++j)
                bfr[j] = *(const bf16x8*)&Bl[buf][j * 16 + (lane & 15)][ks * 32 + (lane >> 4) * 8];
            #pragma unroll
            for (int i = 0; i < 4; ++i)
                #pragma unroll
                for (int j = 0; j < 4; ++j)
                    acc[i][j] = __builtin_amdgcn_mfma_f32_16x16x32_bf16(af[i], bfr[j], acc[i][j], 0, 0, 0);
        }
    };

    stageA(0, 0); stageB(0, 0);
    __syncthreads();
    int nk = K / 64;
    int cur = 0;
    for (int t = 0; t < nk; ++t) {
        if (t + 1 < nk) { stageA(cur ^ 1, (t + 1) * 64); stageB(cur ^ 1, (t + 1) * 64); }
        compute(cur);
        __syncthreads();
        cur ^= 1;
    }

    #pragma unroll
    for (int i = 0; i < 4; ++i) {
        int row = wv * 64 + i * 16 + (lane >> 4) * 4;
        #pragma unroll
        for (int j = 0; j < 4; ++j) {
            int col = n0 + j * 16 + (lane & 15);
            float bv = bias[col];
            #pragma unroll
            for (int r = 0; r < 4; ++r) {
                float v = acc[i][j][r] + bv;
                if constexpr (OUT_BF16) ((ushort_t*)C)[(size_t)(row + r) * N + col] = f2bf(v);
                else                    ((float*)C)[(size_t)(row + r) * N + col] = v;
            }
        }
    }
}

// ---------------------------------------------------------------------------
// Fused sLSTM step: gh (block-diagonal MFMA GEMM) + gate elementwise.
// grid: 256 blocks = head(4) x ochunk(64 of 16 o's); 256 threads, wave = gate.
// h kept as hi+lo bf16 pair (fp32-accurate via 2 MFMAs); ping-pong buffers.
// ---------------------------------------------------------------------------
__global__ __launch_bounds__(256)
void lstm_step_kernel(const ushort_t* __restrict__ R,      // [4][4][1024][1024] bf16
                      const ushort_t* __restrict__ h_hi,   // [16][4096] (rows 8..15 pad)
                      const ushort_t* __restrict__ h_lo,
                      const float* __restrict__ Gx,        // [256][16384]
                      float* __restrict__ stc, float* __restrict__ stn,
                      float* __restrict__ stm,
                      ushort_t* __restrict__ ho_hi, ushort_t* __restrict__ ho_lo,
                      float* __restrict__ hs, int t) {
    __shared__ float gh_l[4][16][8];
    int tid  = threadIdx.x;
    int lane = tid & 63;
    int g    = tid >> 6;                 // gate = wave
    int head = blockIdx.x >> 6;
    int oc   = blockIdx.x & 63;

    int arow = lane & 15;                // A row (o_local) == B col (b)
    int kseg = (lane >> 4) * 8;

    const ushort_t* Rbase = R + ((size_t)((head * 4 + g) * DH + oc * 16 + arow)) * DH + kseg;
    const ushort_t* Hhi   = h_hi + (size_t)arow * DOUT + head * DH + kseg;
    const ushort_t* Hlo   = h_lo + (size_t)arow * DOUT + head * DH + kseg;

    f32x4 acc = (f32x4){0.f, 0.f, 0.f, 0.f};
    #pragma unroll 8
    for (int ks = 0; ks < 32; ++ks) {
        bf16x8 a  = *(const bf16x8*)(Rbase + ks * 32);
        bf16x8 bh = *(const bf16x8*)(Hhi + ks * 32);
        bf16x8 bl = *(const bf16x8*)(Hlo + ks * 32);
        acc = __builtin_amdgcn_mfma_f32_16x16x32_bf16(a, bh, acc, 0, 0, 0);
        acc = __builtin_amdgcn_mfma_f32_16x16x32_bf16(a, bl, acc, 0, 0, 0);
    }
    // D layout: col=lane&15 (=b), row=(lane>>4)*4+r (=o_local)
    int bcol  = lane & 15;
    int orow0 = (lane >> 4) * 4;
    if (bcol < 8) {
        #pragma unroll
        for (int r = 0; r < 4; ++r) gh_l[g][orow0 + r][bcol] = acc[r];
    }
    __syncthreads();

    if (tid < 128) {
        int b = tid >> 4, ol = tid & 15;
        int d = head * DH + oc * 16 + ol;
        int idx = b * DOUT + d;
        size_t gxoff = ((size_t)(b * TT + t)) * (4 * DOUT) + d;
        float ip = Gx[gxoff]             + gh_l[0][ol][b];
        float fp = Gx[gxoff + DOUT]      + gh_l[1][ol][b];
        float zp = Gx[gxoff + 2 * DOUT]  + gh_l[2][ol][b];
        float op = Gx[gxoff + 3 * DOUT]  + gh_l[3][ol][b];
        float mo = stm[idx];
        float mn = fmaxf(fp + mo, ip);
        float iv = expf(ip - mn);
        float fv = expf(fp + mo - mn);
        float cv = fv * stc[idx] + iv * tanhf(zp);
        float nv = fv * stn[idx] + iv;
        float sig = 1.f / (1.f + expf(-op));
        float hv = sig * cv / nv;
        stc[idx] = cv; stn[idx] = nv; stm[idx] = mn;
        hs[((size_t)(b * TT + t)) * DOUT + d] = hv;
        ushort_t hi = f2bf(hv);
        ho_hi[idx] = hi;
        ho_lo[idx] = f2bf(hv - bf2f(hi));
    }
}

// ---------------------------------------------------------------------------
// conv3d 3x3x3 pad=1: one block per (b,t); LDS-staged input slice + weights.
// ---------------------------------------------------------------------------
__global__ __launch_bounds__(256)
void conv3d_kernel(const float* __restrict__ in, const float* __restrict__ w,
                   const float* __restrict__ bias, float* __restrict__ out, int relu) {
    __shared__ float xin[CIN][3][256];      // 48 KB
    __shared__ float wl[CIN][27][16];       // 27 KB, o-fastest
    int b = blockIdx.x >> 5, t = blockIdx.x & 31;
    int tid = threadIdx.x;

    for (int i = tid; i < CIN * 27 * 16; i += 256) {
        int o = i & 15, r = i >> 4;
        int k = r % 27, ci = r / 27;
        wl[ci][k][o] = w[(size_t)(o * CIN + ci) * 27 + k];
    }
    for (int i = tid; i < CIN * 3 * 256; i += 256) {
        int hw = i & 255, r = i >> 8;
        int kt = r % 3, ci = r / 3;
        int tt = t + kt - 1;
        xin[ci][kt][hw] = ((unsigned)tt < TT)
            ? in[((size_t)(b * CIN + ci) * TT + tt) * 256 + hw] : 0.f;
    }
    __syncthreads();

    int h = tid >> 4, wx = tid & 15;
    f32x4 a0 = *(const f32x4*)&bias[0];
    f32x4 a1 = *(const f32x4*)&bias[4];
    f32x4 a2 = *(const f32x4*)&bias[8];
    f32x4 a3 = *(const f32x4*)&bias[12];

    for (int ci = 0; ci < CIN; ++ci) {
        #pragma unroll
        for (int kt = 0; kt < 3; ++kt) {
            #pragma unroll
            for (int kh = 0; kh < 3; ++kh) {
                int h2 = h + kh - 1;
                if ((unsigned)h2 >= HH) continue;
                #pragma unroll
                for (int kw = 0; kw < 3; ++kw) {
                    int w2 = wx + kw - 1;
                    if ((unsigned)w2 >= WW) continue;
                    float xv = xin[ci][kt][h2 * 16 + w2];
                    int k = kt * 9 + kh * 3 + kw;
                    f32x4 w0 = *(const f32x4*)&wl[ci][k][0];
                    f32x4 w1 = *(const f32x4*)&wl[ci][k][4];
                    f32x4 w2v = *(const f32x4*)&wl[ci][k][8];
                    f32x4 w3 = *(const f32x4*)&wl[ci][k][12];
                    a0 += xv * w0; a1 += xv * w1; a2 += xv * w2v; a3 += xv * w3;
                }
            }
        }
    }
    float accs[16];
    #pragma unroll
    for (int i = 0; i < 4; ++i) { accs[i] = a0[i]; accs[4+i] = a1[i]; accs[8+i] = a2[i]; accs[12+i] = a3[i]; }
    #pragma unroll
    for (int o = 0; o < 16; ++o) {
        float v = accs[o];
        if (relu) v = fmaxf(v, 0.f);
        out[((size_t)(b * COUT + o) * TT + t) * 256 + tid] = v;
    }
}

// ---------------------------------------------------------------------------
// instance norm over (T,H,W) per (b,c) + relu, in place. 128 blocks.
// ---------------------------------------------------------------------------
__global__ void inorm_relu_kernel(float* __restrict__ y) {
    __shared__ float s1[256], s2[256];
    float* p = y + (size_t)blockIdx.x * SPAT;
    float sum = 0.f, sq = 0.f;
    for (int i = threadIdx.x; i < SPAT; i += 256) {
        float v = p[i];
        sum += v; sq += v * v;
    }
    s1[threadIdx.x] = sum; s2[threadIdx.x] = sq;
    __syncthreads();
    for (int s = 128; s > 0; s >>= 1) {
        if (threadIdx.x < s) { s1[threadIdx.x] += s1[threadIdx.x + s]; s2[threadIdx.x] += s2[threadIdx.x + s]; }
        __syncthreads();
    }
    float mu = s1[0] / (float)SPAT;
    float var = s2[0] / (float)SPAT - mu * mu;
    float rs = rsqrtf(var + 1e-5f);
    for (int i = threadIdx.x; i < SPAT; i += 256) {
        float v = (p[i] - mu) * rs;
        p[i] = fmaxf(v, 0.f);
    }
}

// ---------------------------------------------------------------------------
// final combine
// ---------------------------------------------------------------------------
__global__ void combine_kernel(const float* __restrict__ hs,
                               const float* __restrict__ out3d,
                               const float* __restrict__ attn_w,
                               const float* __restrict__ attn_b,
                               float* __restrict__ out) {
    int idx = blockIdx.x * 256 + threadIdx.x;
    int hw = idx & 255;
    int t  = (idx >> 8) & 31;
    int b  = idx >> 13;
    const float* hrow = hs + ((size_t)(b * TT + t)) * DOUT;
    float dot = attn_b[0];
    float sv[16], ov[16];
    #pragma unroll
    for (int ch = 0; ch < 16; ++ch) {
        float s  = hrow[ch * 256 + hw];
        float o3 = out3d[(((size_t)(b * COUT + ch) * TT + t)) * 256 + hw];
        sv[ch] = s; ov[ch] = o3;
        dot += attn_w[ch] * s + attn_w[16 + ch] * o3;
    }
    float alpha = 1.f / (1.f + expf(-dot));
    #pragma unroll
    for (int ch = 0; ch < 16; ++ch) {
        out[(((size_t)(b * COUT + ch) * TT + t)) * 256 + hw] =
            alpha * ov[ch] + (1.f - alpha) * sv[ch];
    }
}

// ---------------------------------------------------------------------------
extern "C" void kernel_launch(void* const* d_in, const int* in_sizes, int n_in,
                              void* d_out, int out_size, void* d_ws, size_t ws_size,
                              hipStream_t stream) {
    const float* x      = (const float*)d_in[0];
    const float* c1_w   = (const float*)d_in[1];
    const float* c1_b   = (const float*)d_in[2];
    const float* c2_w   = (const float*)d_in[3];
    const float* c2_b   = (const float*)d_in[4];
    const float* c3_w   = (const float*)d_in[5];
    const float* c3_b   = (const float*)d_in[6];
    const float* pre_w  = (const float*)d_in[7];
    const float* pre_b  = (const float*)d_in[8];
    const float* lstm_W = (const float*)d_in[9];
    const float* lstm_b = (const float*)d_in[10];
    const float* lstm_R = (const float*)d_in[11];
    const float* attn_w = (const float*)d_in[12];
    const float* attn_b = (const float*)d_in[13];
    float* out = (float*)d_out;

    // workspace carve (fp32 first, then bf16; all 16B aligned)
    float* wsf = (float*)d_ws;
    float* y1    = wsf;                // 1048576
    float* y2    = y1 + 1048576;       // 1048576
    float* out3d = y2 + 1048576;       // 1048576
    float* hs    = out3d + 1048576;    // 1048576
    float* Gx    = hs + 1048576;       // 4194304
    float* stc   = Gx + 4194304;       // 32768
    float* stn   = stc + 32768;        // 32768
    float* stm   = stn + 32768;        // 32768
    ushort_t* xt    = (ushort_t*)(stm + 32768);   // 1048576
    ushort_t* xs2b  = xt + 1048576;               // 1048576
    ushort_t* R_bf  = xs2b + 1048576;             // 16777216
    ushort_t* hA_hi = R_bf + 16777216;            // 65536 (16 x 4096)
    ushort_t* hA_lo = hA_hi + 65536;              // 65536
    ushort_t* hB_hi = hA_lo + 65536;              // 65536
    ushort_t* hB_lo = hB_hi + 65536;              // 65536

    // zero c,n,m (contiguous fp32) and all four h buffers (contiguous bf16)
    hipMemsetAsync(stc, 0, 3 * 32768 * sizeof(float), stream);
    hipMemsetAsync(hA_hi, 0, 4 * 65536 * sizeof(ushort_t), stream);

    // pack x -> bf16 sequence layout; convert R -> bf16 once
    pack_xt_kernel<<<1024, 256, 0, stream>>>(x, xt);
    cvt_bf16_kernel<<<2048, 256, 0, stream>>>(lstm_R, R_bf, 16777216 / 4);

    // convs
    conv3d_kernel<<<256, 256, 0, stream>>>(x, c1_w, c1_b, y1, 0);
    inorm_relu_kernel<<<128, 256, 0, stream>>>(y1);
    conv3d_kernel<<<256, 256, 0, stream>>>(y1, c2_w, c2_b, y2, 1);
    conv3d_kernel<<<256, 256, 0, stream>>>(y2, c3_w, c3_b, out3d, 1);

    // pre-projection -> xs2 (bf16); gate projection -> Gx (fp32)
    mfma_gemm_kernel<true><<<DOUT / 64, 256, 0, stream>>>(xt, pre_w, pre_b, xs2b, DOUT, DIN);
    mfma_gemm_kernel<false><<<4 * DOUT / 64, 256, 0, stream>>>(xs2b, lstm_W, lstm_b, Gx, 4 * DOUT, DOUT);

    // recurrence: 32 fused steps, ping-pong h buffers
    for (int t = 0; t < TT; ++t) {
        const ushort_t* hi_in = (t & 1) ? hB_hi : hA_hi;
        const ushort_t* lo_in = (t & 1) ? hB_lo : hA_lo;
        ushort_t* hi_out = (t & 1) ? hA_hi : hB_hi;
        ushort_t* lo_out = (t & 1) ? hA_lo : hB_lo;
        lstm_step_kernel<<<256, 256, 0, stream>>>(R_bf, hi_in, lo_in, Gx,
                                                  stc, stn, stm, hi_out, lo_out, hs, t);
    }

    // combine
    combine_kernel<<<256, 256, 0, stream>>>(hs, out3d, attn_w, attn_b, out);
}